// Round 12
// baseline (224.895 us; speedup 1.0000x reference)
//
#include <hip/hip_runtime.h>

#define D 128
#define D2 256
#define BSH 5        // bucket = dst>>5 (32 nodes/bucket); N=50000 -> 1563 buckets
#define BNODES 32
#define NBMAX 2048
#define NSEG 8       // sub-cursors per bucket (cuts same-address atomic chain 8x)
#define SEGCAP 128   // slots per segment (mean 64, sigma 8 -> 8-sigma headroom)
#define CAP 1024     // NSEG*SEGCAP words per bucket in pairbuf
#define REP 32       // BN-stat accumulator replicas
#define CSTRIDE 16   // each sub-cursor on its own 64B line
#define CURWORDS (NBMAX * NSEG * CSTRIDE)
#define ZWORDS (2 * REP * 256 + CURWORDS)  // bnsum+bnsumsq+cursor zero range

typedef __attribute__((ext_vector_type(8))) short short8;
typedef __attribute__((ext_vector_type(4))) float f32x4;

__device__ inline unsigned short f2b(float f) {
  unsigned u = __float_as_uint(f);
  unsigned r = (u + 0x7FFFu + ((u >> 16) & 1u)) >> 16;
  return (unsigned short)r;
}
__device__ inline float lo2f(unsigned u) { return __uint_as_float(u << 16); }
__device__ inline float hi2f(unsigned u) { return __uint_as_float(u & 0xffff0000u); }

// ---------------------------------------------------------------------------
// PREP (one dispatch): weight conversion into MFMA B-fragment order,
// mb = bf16( t*log2e * (relu(x)+1e-7) )  (+zero row at N) -- exp argument
// PRE-SCALED so agg2 uses a raw v_exp_f32 (2^u) with no per-element muls.
// Also zero-inits bnsum/bnsumsq/cursor.
// ---------------------------------------------------------------------------
__global__ __launch_bounds__(256) void prep_kernel(
    const float* __restrict__ x, const float* __restrict__ W1,
    const float* __restrict__ W2, const float* __restrict__ tptr,
    unsigned short* __restrict__ mb,
    unsigned short* __restrict__ W1f, unsigned short* __restrict__ W2f,
    float* __restrict__ zbase, int total4) {
  int idx = blockIdx.x * 256 + threadIdx.x;
  if (idx < 32768) {
    int k = idx >> 8, n = idx & 255;
    int t = n >> 4, m16 = n & 15;
    int kk = k >> 5, quad = (k >> 3) & 3, j = k & 7;
    W1f[(((t * 4 + kk) * 64 + quad * 16 + m16) << 3) + j] = f2b(W1[idx]);
  } else if (idx < 65536) {
    int i = idx - 32768;
    int k = i >> 7, n = i & 127;
    int t = n >> 4, m16 = n & 15;
    int kk = k >> 5, quad = (k >> 3) & 3, j = k & 7;
    W2f[(((t * 8 + kk) * 64 + quad * 16 + m16) << 3) + j] = f2b(W2[i]);
  } else if (idx < 65536 + total4) {
    int i = idx - 65536;
    float scl = tptr[0] * 1.4426950408889634f;  // t * log2(e)
    float4 v = reinterpret_cast<const float4*>(x)[i];
    unsigned lo = (unsigned)f2b(scl * (fmaxf(v.x, 0.f) + 1e-7f)) |
                  ((unsigned)f2b(scl * (fmaxf(v.y, 0.f) + 1e-7f)) << 16);
    unsigned hi = (unsigned)f2b(scl * (fmaxf(v.z, 0.f) + 1e-7f)) |
                  ((unsigned)f2b(scl * (fmaxf(v.w, 0.f) + 1e-7f)) << 16);
    reinterpret_cast<uint2*>(mb)[i] = make_uint2(lo, hi);
  } else if (idx < 65536 + total4 + 32) {
    reinterpret_cast<uint2*>(mb)[idx - 65536] = make_uint2(0u, 0u);  // zero row N
  } else if (idx < 65536 + total4 + 32 + ZWORDS) {
    zbase[idx - (65536 + total4 + 32)] = 0.f;
  }
}

// ---------------------------------------------------------------------------
// One-pass edge scatter with SUB-CURSORS. Round-11 measurement: one cursor
// per bucket = 512 serialized same-address RMWs (~225cy each) = 48us.
// NSEG=8 sub-cursors (segment = e&7, each on its own 64B line) cut the
// per-address chain to 64 -> ~6us predicted. Scatter store lands in L2.
// ---------------------------------------------------------------------------
__global__ __launch_bounds__(256) void scat_kernel(const int* __restrict__ ei,
                                                   int* __restrict__ cursor,
                                                   unsigned* __restrict__ pairbuf,
                                                   int E) {
  int stride = gridDim.x * 256;
  for (int e = blockIdx.x * 256 + threadIdx.x; e < E; e += stride) {
    int dst = ei[E + e];
    int src = ei[e];
    int b = dst >> BSH;
    int s = e & (NSEG - 1);
    int r = atomicAdd(&cursor[((b << 3) + s) * CSTRIDE], 1);
    if (r < SEGCAP)
      pairbuf[(size_t)b * CAP + (s << 7) + r] =
          (unsigned)src | ((unsigned)(dst & (BNODES - 1)) << 16);
  }
}

// ---------------------------------------------------------------------------
// Fused bucket-CSR + aggregation. One block (512 thr = 8 waves) per bucket.
// CSR build reads the NSEG segments per bucket. Gather loop: 2 nodes/wave
// (32 lanes x 8B uint2), lane-local accumulators, 4-edge groups at depth 2
// (round-7 proven config). x residual row hoisted above the gather.
// exp pre-scaled (mb = t*log2e*m): e = v_exp_f32(u) = 2^u; num accumulates
// e*u, rescaled once by ln2/t in the epilogue.
//   h0b[n][d] = bf16( (ln2/t)*num/(den+1e-16) + x[n][d] )
// ---------------------------------------------------------------------------
__global__ __launch_bounds__(512) void agg2_kernel(const float* __restrict__ x,
                                                   const unsigned short* __restrict__ mb,
                                                   const unsigned* __restrict__ pairbuf,
                                                   const int* __restrict__ cursor,
                                                   const float* __restrict__ tptr,
                                                   unsigned short* __restrict__ h0b, int N) {
  __shared__ int soff[CAP + 4 * BNODES];
  __shared__ int cnt[BNODES], off[BNODES], run[BNODES], pcnt[BNODES];
  __shared__ int segc[NSEG];
  int b = blockIdx.x;
  int tid = threadIdx.x;
  if (tid < BNODES) { cnt[tid] = 0; run[tid] = 0; }
  if (tid >= 64 && tid < 64 + NSEG)
    segc[tid - 64] = min(cursor[((b << 3) + (tid - 64)) * CSTRIDE], SEGCAP);
  __syncthreads();
  for (int s = 0; s < NSEG; ++s) {
    const unsigned* pb = pairbuf + (size_t)b * CAP + (s << 7);
    int c = segc[s];
    for (int j = tid; j < c; j += 512) atomicAdd(&cnt[pb[j] >> 16], 1);
  }
  __syncthreads();
  if (tid < BNODES) {  // exclusive scan over counts padded to multiple of 4
    int c = cnt[tid];
    int pc = (c + 3) & ~3;
    pcnt[tid] = pc;
    int s = pc;
#pragma unroll
    for (int st = 1; st < 32; st <<= 1) {
      int u = __shfl_up(s, st, 32);
      if ((tid & 31) >= st) s += u;
    }
    off[tid] = s - pc;
  }
  __syncthreads();
  for (int s = 0; s < NSEG; ++s) {
    const unsigned* pb = pairbuf + (size_t)b * CAP + (s << 7);
    int c = segc[s];
    for (int j = tid; j < c; j += 512) {
      unsigned p = pb[j];
      int dl = p >> 16;
      int r = atomicAdd(&run[dl], 1);
      soff[off[dl] + r] = (int)(p & 0xffffu) << 8;  // byte offset of mb row
    }
  }
  if (tid < BNODES) {  // pad with dummy src = N (zero row: u=0 -> e=1, p=0)
    int o = off[tid];
    for (int r = cnt[tid]; r < pcnt[tid]; ++r) soff[o + r] = N << 8;
  }
  __syncthreads();

  int w = tid >> 6;
  int l = tid & 63;
  int half = l >> 5;   // which node of the wave's pair
  int l32 = l & 31;
  float numscale = 0.69314718055994531f / tptr[0];  // ln2 / t
  int laneoff = l32 << 3;  // lane's 8B (4 feats) within a 256B row
  const char* mbase = (const char*)mb;

#define PROC(W)                                        \
  do {                                                 \
    float u0 = lo2f((W).x), u1 = hi2f((W).x);          \
    float u2 = lo2f((W).y), u3 = hi2f((W).y);          \
    float e0, e1, e2, e3;                              \
    asm("v_exp_f32 %0, %1" : "=v"(e0) : "v"(u0));      \
    asm("v_exp_f32 %0, %1" : "=v"(e1) : "v"(u1));      \
    asm("v_exp_f32 %0, %1" : "=v"(e2) : "v"(u2));      \
    asm("v_exp_f32 %0, %1" : "=v"(e3) : "v"(u3));      \
    den0 += e0; num0 = fmaf(e0, u0, num0);             \
    den1 += e1; num1 = fmaf(e1, u1, num1);             \
    den2 += e2; num2 = fmaf(e2, u2, num2);             \
    den3 += e3; num3 = fmaf(e3, u3, num3);             \
  } while (0)

#pragma unroll
  for (int p = 0; p < 2; ++p) {
    int ln = (p << 4) | (w << 1) | half;
    int n = (b << BSH) + ln;
    if (n >= N) continue;
    int s0 = off[ln];
    int dn = pcnt[ln];
    size_t idx = ((size_t)n << 7) + (l32 << 2);
    float4 xv = *reinterpret_cast<const float4*>(x + idx);  // hoisted: hides under gather
    float den0 = 0.f, num0 = 0.f, den1 = 0.f, num1 = 0.f;
    float den2 = 0.f, num2 = 0.f, den3 = 0.f, num3 = 0.f;
    if (dn > 0) {
      uint2 uu[4];
#pragma unroll
      for (int q = 0; q < 4; ++q)
        uu[q] = *(const uint2*)(mbase + (soff[s0 + q] | laneoff));
      for (int j = 4; j < dn; j += 4) {
        uint2 vv[4];
#pragma unroll
        for (int q = 0; q < 4; ++q)
          vv[q] = *(const uint2*)(mbase + (soff[s0 + j + q] | laneoff));
#pragma unroll
        for (int q = 0; q < 4; ++q) PROC(uu[q]);
#pragma unroll
        for (int q = 0; q < 4; ++q) uu[q] = vv[q];
      }
#pragma unroll
      for (int q = 0; q < 4; ++q) PROC(uu[q]);
      float fnpad = (float)(dn - cnt[ln]);
      den0 -= fnpad; den1 -= fnpad; den2 -= fnpad; den3 -= fnpad;
    }
    float v0 = num0 * numscale / (den0 + 1e-16f) + xv.x;
    float v1 = num1 * numscale / (den1 + 1e-16f) + xv.y;
    float v2 = num2 * numscale / (den2 + 1e-16f) + xv.z;
    float v3 = num3 * numscale / (den3 + 1e-16f) + xv.w;
    uint2 o;
    o.x = (unsigned)f2b(v0) | ((unsigned)f2b(v1) << 16);
    o.y = (unsigned)f2b(v2) | ((unsigned)f2b(v3) << 16);
    *reinterpret_cast<uint2*>(h0b + idx) = o;
  }
#undef PROC
}

// ---------------------------------------------------------------------------
// GEMM1 STATS-ONLY (MFMA bf16): BN column stats of h0b @ W1.
// NO h1 store -- h1 is recomputed in gemm2. Stats go to REPLICATED
// accumulators (replica = blockIdx & 31).
// ---------------------------------------------------------------------------
__global__ __launch_bounds__(256) void gemm1_stats(
    const unsigned short* __restrict__ h0b, const unsigned short* __restrict__ W1f,
    float* __restrict__ bnsum, float* __restrict__ bnsumsq, int M) {
  int tid = threadIdx.x;
  int w = tid >> 6;
  int l = tid & 63;
  int m16 = l & 15;
  int quad = l >> 4;
  int r0 = blockIdx.x * 64;

  f32x4 acc[4][4];
#pragma unroll
  for (int rt = 0; rt < 4; ++rt)
#pragma unroll
    for (int ct = 0; ct < 4; ++ct) acc[rt][ct] = (f32x4){0.f, 0.f, 0.f, 0.f};

#pragma unroll
  for (int kk = 0; kk < 4; ++kk) {
    short8 bfr[4];
#pragma unroll
    for (int ct = 0; ct < 4; ++ct)
      bfr[ct] = *reinterpret_cast<const short8*>(
          W1f + ((((w * 4 + ct) * 4 + kk) * 64 + l) << 3));
    short8 a[4];
#pragma unroll
    for (int rt = 0; rt < 4; ++rt) {
      int row = min(r0 + rt * 16 + m16, M - 1);
      a[rt] = *reinterpret_cast<const short8*>(h0b + (size_t)row * D + kk * 32 + quad * 8);
    }
#pragma unroll
    for (int rt = 0; rt < 4; ++rt)
#pragma unroll
      for (int ct = 0; ct < 4; ++ct)
        acc[rt][ct] = __builtin_amdgcn_mfma_f32_16x16x32_bf16(a[rt], bfr[ct], acc[rt][ct], 0, 0, 0);
  }

  int rep = (blockIdx.x & (REP - 1)) << 8;
#pragma unroll
  for (int ct = 0; ct < 4; ++ct) {
    int col = w * 64 + ct * 16 + m16;
    float cs = 0.f, cq = 0.f;
#pragma unroll
    for (int rt = 0; rt < 4; ++rt) {
      int rloc = rt * 16 + quad * 4;
#pragma unroll
      for (int reg = 0; reg < 4; ++reg) {
        float val = acc[rt][ct][reg];
        if (r0 + rloc + reg < M) {
          cs += val;
          cq += val * val;
        }
      }
    }
    cs += __shfl_xor(cs, 16, 64);
    cs += __shfl_xor(cs, 32, 64);
    cq += __shfl_xor(cq, 16, 64);
    cq += __shfl_xor(cq, 32, 64);
    if (quad == 0) {
      atomicAdd(&bnsum[rep + col], cs);
      atomicAdd(&bnsumsq[rep + col], cq);
    }
  }
}

// ---------------------------------------------------------------------------
// GEMM2 (MFMA bf16): out = x + relu(LN( relu(BN(h0@W1)) @ W2 + b2 ))
// Phase A: recompute h1 = h0@W1 for this 64-row tile, BN+ReLU in f32 regs,
//          f2b into the 36.9KB LDS transpose tile.
// Phase B: second MFMA from LDS, LN, residual, store.
// No h1 global traffic at all.
// ---------------------------------------------------------------------------
__global__ __launch_bounds__(256) void gemm2_mfma(
    const unsigned short* __restrict__ h0b, const unsigned short* __restrict__ W1f,
    const unsigned short* __restrict__ W2f, const float* __restrict__ b2,
    const float* __restrict__ bnsum, const float* __restrict__ bnsumsq,
    const float* __restrict__ bng, const float* __restrict__ bnb,
    const float* __restrict__ lng, const float* __restrict__ lnb,
    const float* __restrict__ x, float* __restrict__ out, int M) {
  __shared__ unsigned short lt[4][64][72];  // 36.9 KB BN+ReLU'd h1 tile
  __shared__ float lnp[64][2], lnp2[64][2];
  __shared__ float sS[D2], sH[D2];
  int tid = threadIdx.x;
  {
    float s = 0.f, q = 0.f;
#pragma unroll
    for (int r = 0; r < REP; ++r) {
      s += bnsum[(r << 8) + tid];
      q += bnsumsq[(r << 8) + tid];
    }
    float invM = 1.f / (float)M;
    float mu = s * invM;
    float var = q * invM - mu * mu;
    float sc = bng[tid] * rsqrtf(var + 1e-5f);
    sS[tid] = sc;
    sH[tid] = bnb[tid] - mu * sc;
  }
  __syncthreads();

  int w = tid >> 6;
  int l = tid & 63;
  int m16 = l & 15;
  int quad = l >> 4;
  int r0 = blockIdx.x * 64;

  // ---- Phase A: h1 tile -> BN+ReLU -> LDS
  {
    f32x4 acc[4][4];
#pragma unroll
    for (int rt = 0; rt < 4; ++rt)
#pragma unroll
      for (int ct = 0; ct < 4; ++ct) acc[rt][ct] = (f32x4){0.f, 0.f, 0.f, 0.f};

#pragma unroll
    for (int kk = 0; kk < 4; ++kk) {
      short8 bfr[4];
#pragma unroll
      for (int ct = 0; ct < 4; ++ct)
        bfr[ct] = *reinterpret_cast<const short8*>(
            W1f + ((((w * 4 + ct) * 4 + kk) * 64 + l) << 3));
      short8 a[4];
#pragma unroll
      for (int rt = 0; rt < 4; ++rt) {
        int row = min(r0 + rt * 16 + m16, M - 1);
        a[rt] = *reinterpret_cast<const short8*>(h0b + (size_t)row * D + kk * 32 + quad * 8);
      }
#pragma unroll
      for (int rt = 0; rt < 4; ++rt)
#pragma unroll
        for (int ct = 0; ct < 4; ++ct)
          acc[rt][ct] = __builtin_amdgcn_mfma_f32_16x16x32_bf16(a[rt], bfr[ct], acc[rt][ct], 0, 0, 0);
    }

#pragma unroll
    for (int ct = 0; ct < 4; ++ct) {
      int col = w * 64 + ct * 16 + m16;
      float sc = sS[col];
      float sh = sH[col];
#pragma unroll
      for (int rt = 0; rt < 4; ++rt) {
        int rloc = rt * 16 + quad * 4;
#pragma unroll
        for (int reg = 0; reg < 4; ++reg) {
          float h = fmaxf(acc[rt][ct][reg] * sc + sh, 0.f);
          lt[w][rloc + reg][ct * 16 + m16] = f2b(h);
        }
      }
    }
  }
  __syncthreads();

  // ---- Phase B: (BN'd h1) @ W2 + b2, LN, residual
  int rb = w >> 1, cb = w & 1;
  f32x4 acc[2][4];
#pragma unroll
  for (int rt = 0; rt < 2; ++rt)
#pragma unroll
    for (int ct = 0; ct < 4; ++ct) acc[rt][ct] = (f32x4){0.f, 0.f, 0.f, 0.f};

#pragma unroll
  for (int kk = 0; kk < 8; ++kk) {
    int base = kk * 32 + quad * 8;  // global k-col of this lane's A fragment
    short8 a[2];
#pragma unroll
    for (int rt = 0; rt < 2; ++rt) {
      int rl = rb * 32 + rt * 16 + m16;
      a[rt] = *reinterpret_cast<const short8*>(&lt[base >> 6][rl][base & 63]);
    }
    short8 bfr[4];
#pragma unroll
    for (int ct = 0; ct < 4; ++ct)
      bfr[ct] = *reinterpret_cast<const short8*>(
          W2f + ((((cb * 4 + ct) * 8 + kk) * 64 + l) << 3));
#pragma unroll
    for (int rt = 0; rt < 2; ++rt)
#pragma unroll
      for (int ct = 0; ct < 4; ++ct)
        acc[rt][ct] = __builtin_amdgcn_mfma_f32_16x16x32_bf16(a[rt], bfr[ct], acc[rt][ct], 0, 0, 0);
  }

  float b2v[4], lgv[4], lbv[4];
#pragma unroll
  for (int ct = 0; ct < 4; ++ct) {
    int col = cb * 64 + ct * 16 + m16;
    b2v[ct] = b2[col];
    lgv[ct] = lng[col];
    lbv[ct] = lnb[col];
  }

#pragma unroll
  for (int rt = 0; rt < 2; ++rt) {
#pragma unroll
    for (int reg = 0; reg < 4; ++reg) {
      float s = 0.f, s2 = 0.f;
#pragma unroll
      for (int ct = 0; ct < 4; ++ct) {
        float v = acc[rt][ct][reg] + b2v[ct];
        s += v;
        s2 += v * v;
      }
#pragma unroll
      for (int msk = 1; msk < 16; msk <<= 1) {
        s += __shfl_xor(s, msk, 64);
        s2 += __shfl_xor(s2, msk, 64);
      }
      if (m16 == 0) {
        int rl = rb * 32 + rt * 16 + quad * 4 + reg;
        lnp[rl][cb] = s;
        lnp2[rl][cb] = s2;
      }
    }
  }
  __syncthreads();

#pragma unroll
  for (int rt = 0; rt < 2; ++rt) {
#pragma unroll
    for (int reg = 0; reg < 4; ++reg) {
      int rl = rb * 32 + rt * 16 + quad * 4 + reg;
      int row = r0 + rl;
      float s = lnp[rl][0] + lnp[rl][1];
      float s2 = lnp2[rl][0] + lnp2[rl][1];
      float mu = s * (1.f / 128.f);
      float var = s2 * (1.f / 128.f) - mu * mu;
      float inv = rsqrtf(var + 1e-5f);
      if (row < M) {
#pragma unroll
        for (int ct = 0; ct < 4; ++ct) {
          int col = cb * 64 + ct * 16 + m16;
          float v = acc[rt][ct][reg] + b2v[ct];
          float h = fmaxf((v - mu) * inv * lgv[ct] + lbv[ct], 0.f);
          out[(size_t)row * D + col] = x[(size_t)row * D + col] + h;
        }
      }
    }
  }
}

extern "C" void kernel_launch(void* const* d_in, const int* in_sizes, int n_in,
                              void* d_out, int out_size, void* d_ws, size_t ws_size,
                              hipStream_t stream) {
  const float* x   = (const float*)d_in[0];
  const int*   ei  = (const int*)d_in[1];
  const float* t   = (const float*)d_in[2];
  const float* W1  = (const float*)d_in[3];
  const float* bng = (const float*)d_in[5];
  const float* bnb = (const float*)d_in[6];
  const float* W2  = (const float*)d_in[7];
  const float* b2  = (const float*)d_in[8];
  const float* lng = (const float*)d_in[9];
  const float* lnb = (const float*)d_in[10];
  float* out = (float*)d_out;

  int N = in_sizes[0] / D;     // 50000
  int E = in_sizes[1] / 2;     // 800000
  size_t nd = (size_t)N * D;
  int nb = (N + BNODES - 1) >> BSH;   // buckets (1563)

  unsigned short* mb  = (unsigned short*)d_ws;        // (nd + 128) bf16 (+zero row)
  unsigned short* h0b = mb + nd + 128;                // nd bf16
  unsigned short* W1f = h0b + nd;                     // 32768 bf16
  unsigned short* W2f = W1f + 32768;                  // 32768 bf16
  float* bnsum   = (float*)(W2f + 32768);             // REP*256
  float* bnsumsq = bnsum + REP * 256;                 // REP*256
  int* cursor    = (int*)(bnsumsq + REP * 256);       // NBMAX*NSEG*CSTRIDE ints
  unsigned* pairbuf = (unsigned*)(cursor + CURWORDS); // nb*CAP words (~6.4MB)

  int total4 = (int)(nd / 4);
  int ptotal = 65536 + total4 + 32 + ZWORDS;
  prep_kernel<<<(ptotal + 255) / 256, 256, 0, stream>>>(x, W1, W2, t, mb, W1f, W2f,
                                                        bnsum, total4);

  scat_kernel<<<2048, 256, 0, stream>>>(ei, cursor, pairbuf, E);
  agg2_kernel<<<nb, 512, 0, stream>>>(x, mb, pairbuf, cursor, t, h0b, N);

  gemm1_stats<<<(N + 63) / 64, 256, 0, stream>>>(h0b, W1f, bnsum, bnsumsq, N);
  gemm2_mfma<<<(N + 63) / 64, 256, 0, stream>>>(h0b, W1f, W2f, b2, bnsum, bnsumsq,
                                                bng, bnb, lng, lnb, x, out, N);
}

// Round 13
// 204.272 us; speedup vs baseline: 1.1010x; 1.1010x over previous
//
#include <hip/hip_runtime.h>

#define D 128
#define D2 256
#define BSH 5        // bucket = dst>>5 (32 nodes/bucket); N=50000 -> 1563 buckets
#define BNODES 32
#define NBMAX 2048
#define CAP 640      // per-bucket edge capacity (mean 512, sigma ~23)
#define EBLK 256     // partition blocks (3125 edges each)
#define REP 32       // BN-stat accumulator replicas
#define ZWORDS (2 * REP * 256)  // bnsum+bnsumsq zero range (cursor/hist fully overwritten)

typedef __attribute__((ext_vector_type(8))) short short8;
typedef __attribute__((ext_vector_type(4))) float f32x4;

__device__ inline unsigned short f2b(float f) {
  unsigned u = __float_as_uint(f);
  unsigned r = (u + 0x7FFFu + ((u >> 16) & 1u)) >> 16;
  return (unsigned short)r;
}
__device__ inline float lo2f(unsigned u) { return __uint_as_float(u << 16); }
__device__ inline float hi2f(unsigned u) { return __uint_as_float(u & 0xffff0000u); }

// ---------------------------------------------------------------------------
// PREP: weight conversion to MFMA B-fragment order, mb = bf16(t*log2e*
// (relu(x)+1e-7)) (+zero row at N), zero-init of bnsum/bnsumsq.
// ---------------------------------------------------------------------------
__global__ __launch_bounds__(256) void prep_kernel(
    const float* __restrict__ x, const float* __restrict__ W1,
    const float* __restrict__ W2, const float* __restrict__ tptr,
    unsigned short* __restrict__ mb,
    unsigned short* __restrict__ W1f, unsigned short* __restrict__ W2f,
    float* __restrict__ zbase, int total4) {
  int idx = blockIdx.x * 256 + threadIdx.x;
  if (idx < 32768) {
    int k = idx >> 8, n = idx & 255;
    int t = n >> 4, m16 = n & 15;
    int kk = k >> 5, quad = (k >> 3) & 3, j = k & 7;
    W1f[(((t * 4 + kk) * 64 + quad * 16 + m16) << 3) + j] = f2b(W1[idx]);
  } else if (idx < 65536) {
    int i = idx - 32768;
    int k = i >> 7, n = i & 127;
    int t = n >> 4, m16 = n & 15;
    int kk = k >> 5, quad = (k >> 3) & 3, j = k & 7;
    W2f[(((t * 8 + kk) * 64 + quad * 16 + m16) << 3) + j] = f2b(W2[i]);
  } else if (idx < 65536 + total4) {
    int i = idx - 65536;
    float scl = tptr[0] * 1.4426950408889634f;  // t * log2(e)
    float4 v = reinterpret_cast<const float4*>(x)[i];
    unsigned lo = (unsigned)f2b(scl * (fmaxf(v.x, 0.f) + 1e-7f)) |
                  ((unsigned)f2b(scl * (fmaxf(v.y, 0.f) + 1e-7f)) << 16);
    unsigned hi = (unsigned)f2b(scl * (fmaxf(v.z, 0.f) + 1e-7f)) |
                  ((unsigned)f2b(scl * (fmaxf(v.w, 0.f) + 1e-7f)) << 16);
    reinterpret_cast<uint2*>(mb)[i] = make_uint2(lo, hi);
  } else if (idx < 65536 + total4 + 32) {
    reinterpret_cast<uint2*>(mb)[idx - 65536] = make_uint2(0u, 0u);  // zero row N
  } else if (idx < 65536 + total4 + 32 + ZWORDS) {
    zbase[idx - (65536 + total4 + 32)] = 0.f;
  }
}

// ---------------------------------------------------------------------------
// ATOMIC-FREE partition, pass 1: per-block LDS histogram of dst buckets.
// (Rounds 10-12 showed ANY scheme with ~1M device atomics-with-return costs
// ~45-50us regardless of address spread; counting sort removes them all.)
// ---------------------------------------------------------------------------
__global__ __launch_bounds__(256) void hist_kernel(const int* __restrict__ ei,
                                                   int* __restrict__ hist,
                                                   int E, int nb) {
  __shared__ int cnt[NBMAX];
  int tid = threadIdx.x, blk = blockIdx.x;
  int per = (E + EBLK - 1) / EBLK;
  int c0 = blk * per;
  int nE = min(per, E - c0);
  for (int i = tid; i < nb; i += 256) cnt[i] = 0;
  __syncthreads();
  for (int j = tid; j < nE; j += 256)
    atomicAdd(&cnt[ei[E + c0 + j] >> BSH], 1);
  __syncthreads();
  for (int i = tid; i < nb; i += 256) hist[blk * nb + i] = cnt[i];  // coalesced
}

// ---------------------------------------------------------------------------
// Pass 2: per-bucket exclusive scan over the EBLK block-counts.
// One block (256 thr) per bucket; thread t owns hist[t][b].
// Writes start[t][b] (block t's base within the bucket) and total[b].
// ---------------------------------------------------------------------------
__global__ __launch_bounds__(256) void scan_kernel(const int* __restrict__ hist,
                                                   int* __restrict__ start,
                                                   int* __restrict__ total, int nb) {
  __shared__ int wsum[4];
  int b = blockIdx.x;
  int t = threadIdx.x;
  int l = t & 63, w = t >> 6;
  int v = hist[t * nb + b];
  int s = v;
#pragma unroll
  for (int st = 1; st < 64; st <<= 1) {
    int u = __shfl_up(s, st, 64);
    if (l >= st) s += u;
  }
  if (l == 63) wsum[w] = s;
  __syncthreads();
  int base = 0;
#pragma unroll
  for (int i = 0; i < 4; ++i)
    if (i < w) base += wsum[i];
  start[t * nb + b] = base + s - v;
  if (t == 255) total[b] = base + s;
}

// ---------------------------------------------------------------------------
// Pass 3: scatter edges to their slots. slot = start[blk][b] + LDS run
// counter (LDS atomics only -- cheap). Zero global atomics.
// ---------------------------------------------------------------------------
__global__ __launch_bounds__(256) void scatc_kernel(const int* __restrict__ ei,
                                                    const int* __restrict__ start,
                                                    unsigned* __restrict__ pairbuf,
                                                    int E, int nb) {
  __shared__ int run[NBMAX];
  int tid = threadIdx.x, blk = blockIdx.x;
  int per = (E + EBLK - 1) / EBLK;
  int c0 = blk * per;
  int nE = min(per, E - c0);
  for (int i = tid; i < nb; i += 256) run[i] = 0;
  __syncthreads();
  const int* srow = start + blk * nb;  // 6KB row, stays L1/L2-hot
  for (int j = tid; j < nE; j += 256) {
    int e = c0 + j;
    int dst = ei[E + e];
    int src = ei[e];
    int b = dst >> BSH;
    int r = srow[b] + atomicAdd(&run[b], 1);
    if (r < CAP)
      pairbuf[(size_t)b * CAP + r] =
          (unsigned)src | ((unsigned)(dst & (BNODES - 1)) << 16);
  }
}

// ---------------------------------------------------------------------------
// Fused bucket-CSR + aggregation (round-7 proven config). One block (512
// thr = 8 waves) per bucket; 2 nodes/wave (32 lanes x 8B uint2), lane-local
// accumulators, 4-edge groups at depth 2; x row hoisted above the gather.
// exp pre-scaled: e = v_exp_f32(u) = 2^u; num rescaled by ln2/t once.
//   h0b[n][d] = bf16( (ln2/t)*num/(den+1e-16) + x[n][d] )
// ---------------------------------------------------------------------------
__global__ __launch_bounds__(512) void agg2_kernel(const float* __restrict__ x,
                                                   const unsigned short* __restrict__ mb,
                                                   const unsigned* __restrict__ pairbuf,
                                                   const int* __restrict__ total,
                                                   const float* __restrict__ tptr,
                                                   unsigned short* __restrict__ h0b, int N) {
  __shared__ int soff[CAP + 4 * BNODES];
  __shared__ int cnt[BNODES], off[BNODES], run[BNODES], pcnt[BNODES];
  int b = blockIdx.x;
  int tid = threadIdx.x;
  int Eb = min(total[b], CAP);
  if (tid < BNODES) { cnt[tid] = 0; run[tid] = 0; }
  __syncthreads();
  for (int j = tid; j < Eb; j += 512)
    atomicAdd(&cnt[pairbuf[(size_t)b * CAP + j] >> 16], 1);
  __syncthreads();
  if (tid < BNODES) {  // exclusive scan over counts padded to multiple of 4
    int c = cnt[tid];
    int pc = (c + 3) & ~3;
    pcnt[tid] = pc;
    int s = pc;
#pragma unroll
    for (int st = 1; st < 32; st <<= 1) {
      int u = __shfl_up(s, st, 32);
      if ((tid & 31) >= st) s += u;
    }
    off[tid] = s - pc;
  }
  __syncthreads();
  for (int j = tid; j < Eb; j += 512) {
    unsigned p = pairbuf[(size_t)b * CAP + j];
    int dl = p >> 16;
    int r = atomicAdd(&run[dl], 1);
    soff[off[dl] + r] = (int)(p & 0xffffu) << 8;  // byte offset of mb row
  }
  if (tid < BNODES) {  // pad with dummy src = N (zero row: u=0 -> e=1, p=0)
    int o = off[tid];
    for (int r = cnt[tid]; r < pcnt[tid]; ++r) soff[o + r] = N << 8;
  }
  __syncthreads();

  int w = tid >> 6;
  int l = tid & 63;
  int half = l >> 5;   // which node of the wave's pair
  int l32 = l & 31;
  float numscale = 0.69314718055994531f / tptr[0];  // ln2 / t
  int laneoff = l32 << 3;  // lane's 8B (4 feats) within a 256B row
  const char* mbase = (const char*)mb;

#define PROC(W)                                        \
  do {                                                 \
    float u0 = lo2f((W).x), u1 = hi2f((W).x);          \
    float u2 = lo2f((W).y), u3 = hi2f((W).y);          \
    float e0, e1, e2, e3;                              \
    asm("v_exp_f32 %0, %1" : "=v"(e0) : "v"(u0));      \
    asm("v_exp_f32 %0, %1" : "=v"(e1) : "v"(u1));      \
    asm("v_exp_f32 %0, %1" : "=v"(e2) : "v"(u2));      \
    asm("v_exp_f32 %0, %1" : "=v"(e3) : "v"(u3));      \
    den0 += e0; num0 = fmaf(e0, u0, num0);             \
    den1 += e1; num1 = fmaf(e1, u1, num1);             \
    den2 += e2; num2 = fmaf(e2, u2, num2);             \
    den3 += e3; num3 = fmaf(e3, u3, num3);             \
  } while (0)

#pragma unroll
  for (int p = 0; p < 2; ++p) {
    int ln = (p << 4) | (w << 1) | half;
    int n = (b << BSH) + ln;
    if (n >= N) continue;
    int s0 = off[ln];
    int dn = pcnt[ln];
    size_t idx = ((size_t)n << 7) + (l32 << 2);
    float4 xv = *reinterpret_cast<const float4*>(x + idx);  // hoisted
    float den0 = 0.f, num0 = 0.f, den1 = 0.f, num1 = 0.f;
    float den2 = 0.f, num2 = 0.f, den3 = 0.f, num3 = 0.f;
    if (dn > 0) {
      uint2 uu[4];
#pragma unroll
      for (int q = 0; q < 4; ++q)
        uu[q] = *(const uint2*)(mbase + (soff[s0 + q] | laneoff));
      for (int j = 4; j < dn; j += 4) {
        uint2 vv[4];
#pragma unroll
        for (int q = 0; q < 4; ++q)
          vv[q] = *(const uint2*)(mbase + (soff[s0 + j + q] | laneoff));
#pragma unroll
        for (int q = 0; q < 4; ++q) PROC(uu[q]);
#pragma unroll
        for (int q = 0; q < 4; ++q) uu[q] = vv[q];
      }
#pragma unroll
      for (int q = 0; q < 4; ++q) PROC(uu[q]);
      float fnpad = (float)(dn - cnt[ln]);
      den0 -= fnpad; den1 -= fnpad; den2 -= fnpad; den3 -= fnpad;
    }
    float v0 = num0 * numscale / (den0 + 1e-16f) + xv.x;
    float v1 = num1 * numscale / (den1 + 1e-16f) + xv.y;
    float v2 = num2 * numscale / (den2 + 1e-16f) + xv.z;
    float v3 = num3 * numscale / (den3 + 1e-16f) + xv.w;
    uint2 o;
    o.x = (unsigned)f2b(v0) | ((unsigned)f2b(v1) << 16);
    o.y = (unsigned)f2b(v2) | ((unsigned)f2b(v3) << 16);
    *reinterpret_cast<uint2*>(h0b + idx) = o;
  }
#undef PROC
}

// ---------------------------------------------------------------------------
// GEMM1 STATS-ONLY (MFMA bf16): BN column stats of h0b @ W1. Stats go to
// REPLICATED fire-and-forget float atomics (replica = blockIdx & 31).
// ---------------------------------------------------------------------------
__global__ __launch_bounds__(256) void gemm1_stats(
    const unsigned short* __restrict__ h0b, const unsigned short* __restrict__ W1f,
    float* __restrict__ bnsum, float* __restrict__ bnsumsq, int M) {
  int tid = threadIdx.x;
  int w = tid >> 6;
  int l = tid & 63;
  int m16 = l & 15;
  int quad = l >> 4;
  int r0 = blockIdx.x * 64;

  f32x4 acc[4][4];
#pragma unroll
  for (int rt = 0; rt < 4; ++rt)
#pragma unroll
    for (int ct = 0; ct < 4; ++ct) acc[rt][ct] = (f32x4){0.f, 0.f, 0.f, 0.f};

#pragma unroll
  for (int kk = 0; kk < 4; ++kk) {
    short8 bfr[4];
#pragma unroll
    for (int ct = 0; ct < 4; ++ct)
      bfr[ct] = *reinterpret_cast<const short8*>(
          W1f + ((((w * 4 + ct) * 4 + kk) * 64 + l) << 3));
    short8 a[4];
#pragma unroll
    for (int rt = 0; rt < 4; ++rt) {
      int row = min(r0 + rt * 16 + m16, M - 1);
      a[rt] = *reinterpret_cast<const short8*>(h0b + (size_t)row * D + kk * 32 + quad * 8);
    }
#pragma unroll
    for (int rt = 0; rt < 4; ++rt)
#pragma unroll
      for (int ct = 0; ct < 4; ++ct)
        acc[rt][ct] = __builtin_amdgcn_mfma_f32_16x16x32_bf16(a[rt], bfr[ct], acc[rt][ct], 0, 0, 0);
  }

  int rep = (blockIdx.x & (REP - 1)) << 8;
#pragma unroll
  for (int ct = 0; ct < 4; ++ct) {
    int col = w * 64 + ct * 16 + m16;
    float cs = 0.f, cq = 0.f;
#pragma unroll
    for (int rt = 0; rt < 4; ++rt) {
      int rloc = rt * 16 + quad * 4;
#pragma unroll
      for (int reg = 0; reg < 4; ++reg) {
        float val = acc[rt][ct][reg];
        if (r0 + rloc + reg < M) {
          cs += val;
          cq += val * val;
        }
      }
    }
    cs += __shfl_xor(cs, 16, 64);
    cs += __shfl_xor(cs, 32, 64);
    cq += __shfl_xor(cq, 16, 64);
    cq += __shfl_xor(cq, 32, 64);
    if (quad == 0) {
      atomicAdd(&bnsum[rep + col], cs);
      atomicAdd(&bnsumsq[rep + col], cq);
    }
  }
}

// ---------------------------------------------------------------------------
// GEMM2 (MFMA bf16): out = x + relu(LN( relu(BN(h0@W1)) @ W2 + b2 ))
// Phase A: recompute h1 tile, BN+ReLU in f32 regs, f2b -> LDS transpose.
// Phase B: second MFMA from LDS, LN, residual, store.
// ---------------------------------------------------------------------------
__global__ __launch_bounds__(256) void gemm2_mfma(
    const unsigned short* __restrict__ h0b, const unsigned short* __restrict__ W1f,
    const unsigned short* __restrict__ W2f, const float* __restrict__ b2,
    const float* __restrict__ bnsum, const float* __restrict__ bnsumsq,
    const float* __restrict__ bng, const float* __restrict__ bnb,
    const float* __restrict__ lng, const float* __restrict__ lnb,
    const float* __restrict__ x, float* __restrict__ out, int M) {
  __shared__ unsigned short lt[4][64][72];  // 36.9 KB BN+ReLU'd h1 tile
  __shared__ float lnp[64][2], lnp2[64][2];
  __shared__ float sS[D2], sH[D2];
  int tid = threadIdx.x;
  {
    float s = 0.f, q = 0.f;
#pragma unroll
    for (int r = 0; r < REP; ++r) {
      s += bnsum[(r << 8) + tid];
      q += bnsumsq[(r << 8) + tid];
    }
    float invM = 1.f / (float)M;
    float mu = s * invM;
    float var = q * invM - mu * mu;
    float sc = bng[tid] * rsqrtf(var + 1e-5f);
    sS[tid] = sc;
    sH[tid] = bnb[tid] - mu * sc;
  }
  __syncthreads();

  int w = tid >> 6;
  int l = tid & 63;
  int m16 = l & 15;
  int quad = l >> 4;
  int r0 = blockIdx.x * 64;

  // ---- Phase A: h1 tile -> BN+ReLU -> LDS
  {
    f32x4 acc[4][4];
#pragma unroll
    for (int rt = 0; rt < 4; ++rt)
#pragma unroll
      for (int ct = 0; ct < 4; ++ct) acc[rt][ct] = (f32x4){0.f, 0.f, 0.f, 0.f};

#pragma unroll
    for (int kk = 0; kk < 4; ++kk) {
      short8 bfr[4];
#pragma unroll
      for (int ct = 0; ct < 4; ++ct)
        bfr[ct] = *reinterpret_cast<const short8*>(
            W1f + ((((w * 4 + ct) * 4 + kk) * 64 + l) << 3));
      short8 a[4];
#pragma unroll
      for (int rt = 0; rt < 4; ++rt) {
        int row = min(r0 + rt * 16 + m16, M - 1);
        a[rt] = *reinterpret_cast<const short8*>(h0b + (size_t)row * D + kk * 32 + quad * 8);
      }
#pragma unroll
      for (int rt = 0; rt < 4; ++rt)
#pragma unroll
        for (int ct = 0; ct < 4; ++ct)
          acc[rt][ct] = __builtin_amdgcn_mfma_f32_16x16x32_bf16(a[rt], bfr[ct], acc[rt][ct], 0, 0, 0);
    }

#pragma unroll
    for (int ct = 0; ct < 4; ++ct) {
      int col = w * 64 + ct * 16 + m16;
      float sc = sS[col];
      float sh = sH[col];
#pragma unroll
      for (int rt = 0; rt < 4; ++rt) {
        int rloc = rt * 16 + quad * 4;
#pragma unroll
        for (int reg = 0; reg < 4; ++reg) {
          float h = fmaxf(acc[rt][ct][reg] * sc + sh, 0.f);
          lt[w][rloc + reg][ct * 16 + m16] = f2b(h);
        }
      }
    }
  }
  __syncthreads();

  // ---- Phase B: (BN'd h1) @ W2 + b2, LN, residual
  int rb = w >> 1, cb = w & 1;
  f32x4 acc[2][4];
#pragma unroll
  for (int rt = 0; rt < 2; ++rt)
#pragma unroll
    for (int ct = 0; ct < 4; ++ct) acc[rt][ct] = (f32x4){0.f, 0.f, 0.f, 0.f};

#pragma unroll
  for (int kk = 0; kk < 8; ++kk) {
    int base = kk * 32 + quad * 8;  // global k-col of this lane's A fragment
    short8 a[2];
#pragma unroll
    for (int rt = 0; rt < 2; ++rt) {
      int rl = rb * 32 + rt * 16 + m16;
      a[rt] = *reinterpret_cast<const short8*>(&lt[base >> 6][rl][base & 63]);
    }
    short8 bfr[4];
#pragma unroll
    for (int ct = 0; ct < 4; ++ct)
      bfr[ct] = *reinterpret_cast<const short8*>(
          W2f + ((((cb * 4 + ct) * 8 + kk) * 64 + l) << 3));
#pragma unroll
    for (int rt = 0; rt < 2; ++rt)
#pragma unroll
      for (int ct = 0; ct < 4; ++ct)
        acc[rt][ct] = __builtin_amdgcn_mfma_f32_16x16x32_bf16(a[rt], bfr[ct], acc[rt][ct], 0, 0, 0);
  }

  float b2v[4], lgv[4], lbv[4];
#pragma unroll
  for (int ct = 0; ct < 4; ++ct) {
    int col = cb * 64 + ct * 16 + m16;
    b2v[ct] = b2[col];
    lgv[ct] = lng[col];
    lbv[ct] = lnb[col];
  }

#pragma unroll
  for (int rt = 0; rt < 2; ++rt) {
#pragma unroll
    for (int reg = 0; reg < 4; ++reg) {
      float s = 0.f, s2 = 0.f;
#pragma unroll
      for (int ct = 0; ct < 4; ++ct) {
        float v = acc[rt][ct][reg] + b2v[ct];
        s += v;
        s2 += v * v;
      }
#pragma unroll
      for (int msk = 1; msk < 16; msk <<= 1) {
        s += __shfl_xor(s, msk, 64);
        s2 += __shfl_xor(s2, msk, 64);
      }
      if (m16 == 0) {
        int rl = rb * 32 + rt * 16 + quad * 4 + reg;
        lnp[rl][cb] = s;
        lnp2[rl][cb] = s2;
      }
    }
  }
  __syncthreads();

#pragma unroll
  for (int rt = 0; rt < 2; ++rt) {
#pragma unroll
    for (int reg = 0; reg < 4; ++reg) {
      int rl = rb * 32 + rt * 16 + quad * 4 + reg;
      int row = r0 + rl;
      float s = lnp[rl][0] + lnp[rl][1];
      float s2 = lnp2[rl][0] + lnp2[rl][1];
      float mu = s * (1.f / 128.f);
      float var = s2 * (1.f / 128.f) - mu * mu;
      float inv = rsqrtf(var + 1e-5f);
      if (row < M) {
#pragma unroll
        for (int ct = 0; ct < 4; ++ct) {
          int col = cb * 64 + ct * 16 + m16;
          float v = acc[rt][ct][reg] + b2v[ct];
          float h = fmaxf((v - mu) * inv * lgv[ct] + lbv[ct], 0.f);
          out[(size_t)row * D + col] = x[(size_t)row * D + col] + h;
        }
      }
    }
  }
}

extern "C" void kernel_launch(void* const* d_in, const int* in_sizes, int n_in,
                              void* d_out, int out_size, void* d_ws, size_t ws_size,
                              hipStream_t stream) {
  const float* x   = (const float*)d_in[0];
  const int*   ei  = (const int*)d_in[1];
  const float* t   = (const float*)d_in[2];
  const float* W1  = (const float*)d_in[3];
  const float* bng = (const float*)d_in[5];
  const float* bnb = (const float*)d_in[6];
  const float* W2  = (const float*)d_in[7];
  const float* b2  = (const float*)d_in[8];
  const float* lng = (const float*)d_in[9];
  const float* lnb = (const float*)d_in[10];
  float* out = (float*)d_out;

  int N = in_sizes[0] / D;     // 50000
  int E = in_sizes[1] / 2;     // 800000
  size_t nd = (size_t)N * D;
  int nb = (N + BNODES - 1) >> BSH;   // buckets (1563)

  unsigned short* mb  = (unsigned short*)d_ws;        // (nd + 128) bf16 (+zero row)
  unsigned short* h0b = mb + nd + 128;                // nd bf16
  unsigned short* W1f = h0b + nd;                     // 32768 bf16
  unsigned short* W2f = W1f + 32768;                  // 32768 bf16
  float* bnsum   = (float*)(W2f + 32768);             // REP*256
  float* bnsumsq = bnsum + REP * 256;                 // REP*256
  int* total     = (int*)(bnsumsq + REP * 256);       // NBMAX ints
  int* hist      = total + NBMAX;                     // EBLK*NBMAX ints
  int* startb    = hist + EBLK * NBMAX;               // EBLK*NBMAX ints
  unsigned* pairbuf = (unsigned*)(startb + EBLK * NBMAX);  // nb*CAP words (~4MB)

  int total4 = (int)(nd / 4);
  int ptotal = 65536 + total4 + 32 + ZWORDS;
  prep_kernel<<<(ptotal + 255) / 256, 256, 0, stream>>>(x, W1, W2, t, mb, W1f, W2f,
                                                        bnsum, total4);

  hist_kernel<<<EBLK, 256, 0, stream>>>(ei, hist, E, nb);
  scan_kernel<<<nb, 256, 0, stream>>>(hist, startb, total, nb);
  scatc_kernel<<<EBLK, 256, 0, stream>>>(ei, startb, pairbuf, E, nb);
  agg2_kernel<<<nb, 512, 0, stream>>>(x, mb, pairbuf, total, t, h0b, N);

  gemm1_stats<<<(N + 63) / 64, 256, 0, stream>>>(h0b, W1f, bnsum, bnsumsq, N);
  gemm2_mfma<<<(N + 63) / 64, 256, 0, stream>>>(h0b, W1f, W2f, b2, bnsum, bnsumsq,
                                                bng, bnb, lng, lnb, x, out, N);
}

// Round 15
// 194.734 us; speedup vs baseline: 1.1549x; 1.0490x over previous
//
#include <hip/hip_runtime.h>

#define D 128
#define D2 256
#define BSH 5        // bucket = dst>>5 (32 nodes/bucket); N=50000 -> 1563 buckets
#define BNODES 32
#define NBMAX 2048
#define CAP 640      // per-bucket edge capacity (mean 512, sigma ~23)
#define EBLK 256     // partition blocks (3125 edges each)
#define REP 32       // BN-stat accumulator replicas
#define HSTR 136     // LDS h0-tile row stride in shorts (272B: 16B-aligned, spreads banks)
#define ZWORDS (2 * REP * 256)  // bnsum+bnsumsq zero range

typedef __attribute__((ext_vector_type(8))) short short8;
typedef __attribute__((ext_vector_type(4))) float f32x4;

__device__ inline unsigned short f2b(float f) {
  unsigned u = __float_as_uint(f);
  unsigned r = (u + 0x7FFFu + ((u >> 16) & 1u)) >> 16;
  return (unsigned short)r;
}
__device__ inline float lo2f(unsigned u) { return __uint_as_float(u << 16); }
__device__ inline float hi2f(unsigned u) { return __uint_as_float(u & 0xffff0000u); }

// ---------------------------------------------------------------------------
// PREP + HIST (one dispatch): blocks < pblocks do weight conversion, mb
// table, bnsum/bnsumsq zero-init; blocks >= pblocks run the per-block LDS
// histogram of dst buckets (pass 1 of the atomic-free counting sort).
// ---------------------------------------------------------------------------
__global__ __launch_bounds__(256) void prep_kernel(
    const float* __restrict__ x, const float* __restrict__ W1,
    const float* __restrict__ W2, const float* __restrict__ tptr,
    const int* __restrict__ ei, unsigned short* __restrict__ mb,
    unsigned short* __restrict__ W1f, unsigned short* __restrict__ W2f,
    float* __restrict__ zbase, int* __restrict__ hist,
    int total4, int E, int nb, int pblocks) {
  __shared__ int cnt[NBMAX];
  if ((int)blockIdx.x >= pblocks) {  // ---- histogram branch
    int blk = blockIdx.x - pblocks;
    int tid = threadIdx.x;
    int per = (E + EBLK - 1) / EBLK;
    int c0 = blk * per;
    int nE = min(per, E - c0);
    for (int i = tid; i < nb; i += 256) cnt[i] = 0;
    __syncthreads();
    for (int j = tid; j < nE; j += 256)
      atomicAdd(&cnt[ei[E + c0 + j] >> BSH], 1);
    __syncthreads();
    for (int i = tid; i < nb; i += 256) hist[blk * nb + i] = cnt[i];
    return;
  }
  int idx = blockIdx.x * 256 + threadIdx.x;
  if (idx < 32768) {
    int k = idx >> 8, n = idx & 255;
    int t = n >> 4, m16 = n & 15;
    int kk = k >> 5, quad = (k >> 3) & 3, j = k & 7;
    W1f[(((t * 4 + kk) * 64 + quad * 16 + m16) << 3) + j] = f2b(W1[idx]);
  } else if (idx < 65536) {
    int i = idx - 32768;
    int k = i >> 7, n = i & 127;
    int t = n >> 4, m16 = n & 15;
    int kk = k >> 5, quad = (k >> 3) & 3, j = k & 7;
    W2f[(((t * 8 + kk) * 64 + quad * 16 + m16) << 3) + j] = f2b(W2[i]);
  } else if (idx < 65536 + total4) {
    int i = idx - 65536;
    float scl = tptr[0] * 1.4426950408889634f;  // t * log2(e)
    float4 v = reinterpret_cast<const float4*>(x)[i];
    unsigned lo = (unsigned)f2b(scl * (fmaxf(v.x, 0.f) + 1e-7f)) |
                  ((unsigned)f2b(scl * (fmaxf(v.y, 0.f) + 1e-7f)) << 16);
    unsigned hi = (unsigned)f2b(scl * (fmaxf(v.z, 0.f) + 1e-7f)) |
                  ((unsigned)f2b(scl * (fmaxf(v.w, 0.f) + 1e-7f)) << 16);
    reinterpret_cast<uint2*>(mb)[i] = make_uint2(lo, hi);
  } else if (idx < 65536 + total4 + 32) {
    reinterpret_cast<uint2*>(mb)[idx - 65536] = make_uint2(0u, 0u);  // zero row N
  } else if (idx < 65536 + total4 + 32 + ZWORDS) {
    zbase[idx - (65536 + total4 + 32)] = 0.f;
  }
}

// ---------------------------------------------------------------------------
// Pass 2: per-bucket exclusive scan over the EBLK block-counts.
// ---------------------------------------------------------------------------
__global__ __launch_bounds__(256) void scan_kernel(const int* __restrict__ hist,
                                                   int* __restrict__ start,
                                                   int* __restrict__ total, int nb) {
  __shared__ int wsum[4];
  int b = blockIdx.x;
  int t = threadIdx.x;
  int l = t & 63, w = t >> 6;
  int v = hist[t * nb + b];
  int s = v;
#pragma unroll
  for (int st = 1; st < 64; st <<= 1) {
    int u = __shfl_up(s, st, 64);
    if (l >= st) s += u;
  }
  if (l == 63) wsum[w] = s;
  __syncthreads();
  int base = 0;
#pragma unroll
  for (int i = 0; i < 4; ++i)
    if (i < w) base += wsum[i];
  start[t * nb + b] = base + s - v;
  if (t == 255) total[b] = base + s;
}

// ---------------------------------------------------------------------------
// Pass 3: scatter edges to their slots (LDS run counters only).
// ---------------------------------------------------------------------------
__global__ __launch_bounds__(256) void scatc_kernel(const int* __restrict__ ei,
                                                    const int* __restrict__ start,
                                                    unsigned* __restrict__ pairbuf,
                                                    int E, int nb) {
  __shared__ int run[NBMAX];
  int tid = threadIdx.x, blk = blockIdx.x;
  int per = (E + EBLK - 1) / EBLK;
  int c0 = blk * per;
  int nE = min(per, E - c0);
  for (int i = tid; i < nb; i += 256) run[i] = 0;
  __syncthreads();
  const int* srow = start + blk * nb;
  for (int j = tid; j < nE; j += 256) {
    int e = c0 + j;
    int dst = ei[E + e];
    int src = ei[e];
    int b = dst >> BSH;
    int r = srow[b] + atomicAdd(&run[b], 1);
    if (r < CAP)
      pairbuf[(size_t)b * CAP + r] =
          (unsigned)src | ((unsigned)(dst & (BNODES - 1)) << 16);
  }
}

// ---------------------------------------------------------------------------
// Fused bucket-CSR + aggregation + BN-STATS. Gather is the round-7 proven
// config (untouched). NEW: the epilogue also writes the bucket's 32x128 h0
// tile into LDS (rows >= N zeroed -> contribute exactly 0 to stats); after a
// barrier, each wave runs 16 MFMAs (same fragment layout / K-order as the
// old gemm1_stats -> identical h1 values) and posts REP-replicated
// fire-and-forget stat atomics. Kills the separate stats dispatch AND its
// 12.8MB h0 re-read; agg2's matrix pipe was idle.
// ---------------------------------------------------------------------------
__global__ __launch_bounds__(512) void agg2_kernel(
    const float* __restrict__ x, const unsigned short* __restrict__ mb,
    const unsigned* __restrict__ pairbuf, const int* __restrict__ total,
    const float* __restrict__ tptr, const unsigned short* __restrict__ W1f,
    unsigned short* __restrict__ h0b, float* __restrict__ bnsum,
    float* __restrict__ bnsumsq, int N) {
  __shared__ int soff[CAP + 4 * BNODES];
  __shared__ int cnt[BNODES], off[BNODES], run[BNODES], pcnt[BNODES];
  __shared__ unsigned short h0t[BNODES * HSTR];  // 8.7KB h0 tile
  int b = blockIdx.x;
  int tid = threadIdx.x;
  int Eb = min(total[b], CAP);
  if (tid < BNODES) { cnt[tid] = 0; run[tid] = 0; }
  __syncthreads();
  for (int j = tid; j < Eb; j += 512)
    atomicAdd(&cnt[pairbuf[(size_t)b * CAP + j] >> 16], 1);
  __syncthreads();
  if (tid < BNODES) {  // exclusive scan over counts padded to multiple of 4
    int c = cnt[tid];
    int pc = (c + 3) & ~3;
    pcnt[tid] = pc;
    int s = pc;
#pragma unroll
    for (int st = 1; st < 32; st <<= 1) {
      int u = __shfl_up(s, st, 32);
      if ((tid & 31) >= st) s += u;
    }
    off[tid] = s - pc;
  }
  __syncthreads();
  for (int j = tid; j < Eb; j += 512) {
    unsigned p = pairbuf[(size_t)b * CAP + j];
    int dl = p >> 16;
    int r = atomicAdd(&run[dl], 1);
    soff[off[dl] + r] = (int)(p & 0xffffu) << 8;  // byte offset of mb row
  }
  if (tid < BNODES) {  // pad with dummy src = N (zero row: u=0 -> e=1, p=0)
    int o = off[tid];
    for (int r = cnt[tid]; r < pcnt[tid]; ++r) soff[o + r] = N << 8;
  }
  __syncthreads();

  int w = tid >> 6;
  int l = tid & 63;
  int half = l >> 5;   // which node of the wave's pair
  int l32 = l & 31;
  float numscale = 0.69314718055994531f / tptr[0];  // ln2 / t
  int laneoff = l32 << 3;  // lane's 8B (4 feats) within a 256B row
  const char* mbase = (const char*)mb;

#define PROC(W)                                        \
  do {                                                 \
    float u0 = lo2f((W).x), u1 = hi2f((W).x);          \
    float u2 = lo2f((W).y), u3 = hi2f((W).y);          \
    float e0, e1, e2, e3;                              \
    asm("v_exp_f32 %0, %1" : "=v"(e0) : "v"(u0));      \
    asm("v_exp_f32 %0, %1" : "=v"(e1) : "v"(u1));      \
    asm("v_exp_f32 %0, %1" : "=v"(e2) : "v"(u2));      \
    asm("v_exp_f32 %0, %1" : "=v"(e3) : "v"(u3));      \
    den0 += e0; num0 = fmaf(e0, u0, num0);             \
    den1 += e1; num1 = fmaf(e1, u1, num1);             \
    den2 += e2; num2 = fmaf(e2, u2, num2);             \
    den3 += e3; num3 = fmaf(e3, u3, num3);             \
  } while (0)

#pragma unroll
  for (int p = 0; p < 2; ++p) {
    int ln = (p << 4) | (w << 1) | half;
    int n = (b << BSH) + ln;
    unsigned short* lrow = &h0t[ln * HSTR + (l32 << 2)];
    if (n >= N) {  // invalid row: zero in LDS (contributes 0 to stats)
      *reinterpret_cast<uint2*>(lrow) = make_uint2(0u, 0u);
      continue;
    }
    int s0 = off[ln];
    int dn = pcnt[ln];
    size_t idx = ((size_t)n << 7) + (l32 << 2);
    float4 xv = *reinterpret_cast<const float4*>(x + idx);  // hoisted
    float den0 = 0.f, num0 = 0.f, den1 = 0.f, num1 = 0.f;
    float den2 = 0.f, num2 = 0.f, den3 = 0.f, num3 = 0.f;
    if (dn > 0) {
      uint2 uu[4];
#pragma unroll
      for (int q = 0; q < 4; ++q)
        uu[q] = *(const uint2*)(mbase + (soff[s0 + q] | laneoff));
      for (int j = 4; j < dn; j += 4) {
        uint2 vv[4];
#pragma unroll
        for (int q = 0; q < 4; ++q)
          vv[q] = *(const uint2*)(mbase + (soff[s0 + j + q] | laneoff));
#pragma unroll
        for (int q = 0; q < 4; ++q) PROC(uu[q]);
#pragma unroll
        for (int q = 0; q < 4; ++q) uu[q] = vv[q];
      }
#pragma unroll
      for (int q = 0; q < 4; ++q) PROC(uu[q]);
      float fnpad = (float)(dn - cnt[ln]);
      den0 -= fnpad; den1 -= fnpad; den2 -= fnpad; den3 -= fnpad;
    }
    float v0 = num0 * numscale / (den0 + 1e-16f) + xv.x;
    float v1 = num1 * numscale / (den1 + 1e-16f) + xv.y;
    float v2 = num2 * numscale / (den2 + 1e-16f) + xv.z;
    float v3 = num3 * numscale / (den3 + 1e-16f) + xv.w;
    uint2 o;
    o.x = (unsigned)f2b(v0) | ((unsigned)f2b(v1) << 16);
    o.y = (unsigned)f2b(v2) | ((unsigned)f2b(v3) << 16);
    *reinterpret_cast<uint2*>(h0b + idx) = o;
    *reinterpret_cast<uint2*>(lrow) = o;
  }
#undef PROC
  __syncthreads();

  // ---- BN-stats phase: h1 tile = h0t @ W1, column sums/sumsq.
  {
    int m16 = l & 15;
    int quad = l >> 4;
    int t0 = w << 1;  // wave's two 16-col tiles (8 waves x 2 = 256 cols)
    f32x4 acc[2][2];
#pragma unroll
    for (int rt = 0; rt < 2; ++rt)
#pragma unroll
      for (int c = 0; c < 2; ++c) acc[rt][c] = (f32x4){0.f, 0.f, 0.f, 0.f};
#pragma unroll
    for (int kk = 0; kk < 4; ++kk) {
      short8 a0 = *reinterpret_cast<const short8*>(&h0t[m16 * HSTR + kk * 32 + quad * 8]);
      short8 a1 = *reinterpret_cast<const short8*>(&h0t[(16 + m16) * HSTR + kk * 32 + quad * 8]);
#pragma unroll
      for (int c = 0; c < 2; ++c) {
        short8 bfr = *reinterpret_cast<const short8*>(
            W1f + ((((t0 + c) * 4 + kk) * 64 + l) << 3));
        acc[0][c] = __builtin_amdgcn_mfma_f32_16x16x32_bf16(a0, bfr, acc[0][c], 0, 0, 0);
        acc[1][c] = __builtin_amdgcn_mfma_f32_16x16x32_bf16(a1, bfr, acc[1][c], 0, 0, 0);
      }
    }
    int rep = (b & (REP - 1)) << 8;
#pragma unroll
    for (int c = 0; c < 2; ++c) {
      int col = (t0 + c) * 16 + m16;
      float cs = 0.f, cq = 0.f;
#pragma unroll
      for (int rt = 0; rt < 2; ++rt)
#pragma unroll
        for (int reg = 0; reg < 4; ++reg) {
          float v = acc[rt][c][reg];
          cs += v;
          cq += v * v;
        }
      cs += __shfl_xor(cs, 16, 64);
      cs += __shfl_xor(cs, 32, 64);
      cq += __shfl_xor(cq, 16, 64);
      cq += __shfl_xor(cq, 32, 64);
      if (quad == 0) {
        atomicAdd(&bnsum[rep + col], cs);
        atomicAdd(&bnsumsq[rep + col], cq);
      }
    }
  }
}

// ---------------------------------------------------------------------------
// GEMM2 (MFMA bf16): out = x + relu(LN( relu(BN(h0@W1)) @ W2 + b2 ))
// Phase A: recompute h1 tile, BN+ReLU in f32 regs, f2b -> LDS transpose.
// Phase B: second MFMA from LDS, LN, residual, store.
// ---------------------------------------------------------------------------
__global__ __launch_bounds__(256) void gemm2_mfma(
    const unsigned short* __restrict__ h0b, const unsigned short* __restrict__ W1f,
    const unsigned short* __restrict__ W2f, const float* __restrict__ b2,
    const float* __restrict__ bnsum, const float* __restrict__ bnsumsq,
    const float* __restrict__ bng, const float* __restrict__ bnb,
    const float* __restrict__ lng, const float* __restrict__ lnb,
    const float* __restrict__ x, float* __restrict__ out, int M) {
  __shared__ unsigned short lt[4][64][72];  // 36.9 KB BN+ReLU'd h1 tile
  __shared__ float lnp[64][2], lnp2[64][2];
  __shared__ float sS[D2], sH[D2];
  int tid = threadIdx.x;
  {
    float s = 0.f, q = 0.f;
#pragma unroll
    for (int r = 0; r < REP; ++r) {
      s += bnsum[(r << 8) + tid];
      q += bnsumsq[(r << 8) + tid];
    }
    float invM = 1.f / (float)M;
    float mu = s * invM;
    float var = q * invM - mu * mu;
    float sc = bng[tid] * rsqrtf(var + 1e-5f);
    sS[tid] = sc;
    sH[tid] = bnb[tid] - mu * sc;
  }
  __syncthreads();

  int w = tid >> 6;
  int l = tid & 63;
  int m16 = l & 15;
  int quad = l >> 4;
  int r0 = blockIdx.x * 64;

  // ---- Phase A: h1 tile -> BN+ReLU -> LDS
  {
    f32x4 acc[4][4];
#pragma unroll
    for (int rt = 0; rt < 4; ++rt)
#pragma unroll
      for (int ct = 0; ct < 4; ++ct) acc[rt][ct] = (f32x4){0.f, 0.f, 0.f, 0.f};

#pragma unroll
    for (int kk = 0; kk < 4; ++kk) {
      short8 bfr[4];
#pragma unroll
      for (int ct = 0; ct < 4; ++ct)
        bfr[ct] = *reinterpret_cast<const short8*>(
            W1f + ((((w * 4 + ct) * 4 + kk) * 64 + l) << 3));
      short8 a[4];
#pragma unroll
      for (int rt = 0; rt < 4; ++rt) {
        int row = min(r0 + rt * 16 + m16, M - 1);
        a[rt] = *reinterpret_cast<const short8*>(h0b + (size_t)row * D + kk * 32 + quad * 8);
      }
#pragma unroll
      for (int rt = 0; rt < 4; ++rt)
#pragma unroll
        for (int ct = 0; ct < 4; ++ct)
          acc[rt][ct] = __builtin_amdgcn_mfma_f32_16x16x32_bf16(a[rt], bfr[ct], acc[rt][ct], 0, 0, 0);
    }

#pragma unroll
    for (int ct = 0; ct < 4; ++ct) {
      int col = w * 64 + ct * 16 + m16;
      float sc = sS[col];
      float sh = sH[col];
#pragma unroll
      for (int rt = 0; rt < 4; ++rt) {
        int rloc = rt * 16 + quad * 4;
#pragma unroll
        for (int reg = 0; reg < 4; ++reg) {
          float h = fmaxf(acc[rt][ct][reg] * sc + sh, 0.f);
          lt[w][rloc + reg][ct * 16 + m16] = f2b(h);
        }
      }
    }
  }
  __syncthreads();

  // ---- Phase B: (BN'd h1) @ W2 + b2, LN, residual
  int rb = w >> 1, cb = w & 1;
  f32x4 acc[2][4];
#pragma unroll
  for (int rt = 0; rt < 2; ++rt)
#pragma unroll
    for (int ct = 0; ct < 4; ++ct) acc[rt][ct] = (f32x4){0.f, 0.f, 0.f, 0.f};

#pragma unroll
  for (int kk = 0; kk < 8; ++kk) {
    int base = kk * 32 + quad * 8;  // global k-col of this lane's A fragment
    short8 a[2];
#pragma unroll
    for (int rt = 0; rt < 2; ++rt) {
      int rl = rb * 32 + rt * 16 + m16;
      a[rt] = *reinterpret_cast<const short8*>(&lt[base >> 6][rl][base & 63]);
    }
    short8 bfr[4];
#pragma unroll
    for (int ct = 0; ct < 4; ++ct)
      bfr[ct] = *reinterpret_cast<const short8*>(
          W2f + ((((cb * 4 + ct) * 8 + kk) * 64 + l) << 3));
#pragma unroll
    for (int rt = 0; rt < 2; ++rt)
#pragma unroll
      for (int ct = 0; ct < 4; ++ct)
        acc[rt][ct] = __builtin_amdgcn_mfma_f32_16x16x32_bf16(a[rt], bfr[ct], acc[rt][ct], 0, 0, 0);
  }

  float b2v[4], lgv[4], lbv[4];
#pragma unroll
  for (int ct = 0; ct < 4; ++ct) {
    int col = cb * 64 + ct * 16 + m16;
    b2v[ct] = b2[col];
    lgv[ct] = lng[col];
    lbv[ct] = lnb[col];
  }

#pragma unroll
  for (int rt = 0; rt < 2; ++rt) {
#pragma unroll
    for (int reg = 0; reg < 4; ++reg) {
      float s = 0.f, s2 = 0.f;
#pragma unroll
      for (int ct = 0; ct < 4; ++ct) {
        float v = acc[rt][ct][reg] + b2v[ct];
        s += v;
        s2 += v * v;
      }
#pragma unroll
      for (int msk = 1; msk < 16; msk <<= 1) {
        s += __shfl_xor(s, msk, 64);
        s2 += __shfl_xor(s2, msk, 64);
      }
      if (m16 == 0) {
        int rl = rb * 32 + rt * 16 + quad * 4 + reg;
        lnp[rl][cb] = s;
        lnp2[rl][cb] = s2;
      }
    }
  }
  __syncthreads();

#pragma unroll
  for (int rt = 0; rt < 2; ++rt) {
#pragma unroll
    for (int reg = 0; reg < 4; ++reg) {
      int rl = rb * 32 + rt * 16 + quad * 4 + reg;
      int row = r0 + rl;
      float s = lnp[rl][0] + lnp[rl][1];
      float s2 = lnp2[rl][0] + lnp2[rl][1];
      float mu = s * (1.f / 128.f);
      float var = s2 * (1.f / 128.f) - mu * mu;
      float inv = rsqrtf(var + 1e-5f);
      if (row < M) {
#pragma unroll
        for (int ct = 0; ct < 4; ++ct) {
          int col = cb * 64 + ct * 16 + m16;
          float v = acc[rt][ct][reg] + b2v[ct];
          float h = fmaxf((v - mu) * inv * lgv[ct] + lbv[ct], 0.f);
          out[(size_t)row * D + col] = x[(size_t)row * D + col] + h;
        }
      }
    }
  }
}

extern "C" void kernel_launch(void* const* d_in, const int* in_sizes, int n_in,
                              void* d_out, int out_size, void* d_ws, size_t ws_size,
                              hipStream_t stream) {
  const float* x   = (const float*)d_in[0];
  const int*   ei  = (const int*)d_in[1];
  const float* t   = (const float*)d_in[2];
  const float* W1  = (const float*)d_in[3];
  const float* bng = (const float*)d_in[5];
  const float* bnb = (const float*)d_in[6];
  const float* W2  = (const float*)d_in[7];
  const float* b2  = (const float*)d_in[8];
  const float* lng = (const float*)d_in[9];
  const float* lnb = (const float*)d_in[10];
  float* out = (float*)d_out;

  int N = in_sizes[0] / D;     // 50000
  int E = in_sizes[1] / 2;     // 800000
  size_t nd = (size_t)N * D;
  int nb = (N + BNODES - 1) >> BSH;   // buckets (1563)

  unsigned short* mb  = (unsigned short*)d_ws;        // (nd + 128) bf16 (+zero row)
  unsigned short* h0b = mb + nd + 128;                // nd bf16
  unsigned short* W1f = h0b + nd;                     // 32768 bf16
  unsigned short* W2f = W1f + 32768;                  // 32768 bf16
  float* bnsum   = (float*)(W2f + 32768);             // REP*256
  float* bnsumsq = bnsum + REP * 256;                 // REP*256
  int* total     = (int*)(bnsumsq + REP * 256);       // NBMAX ints
  int* hist      = total + NBMAX;                     // EBLK*NBMAX ints
  int* startb    = hist + EBLK * NBMAX;               // EBLK*NBMAX ints
  unsigned* pairbuf = (unsigned*)(startb + EBLK * NBMAX);  // nb*CAP words (~4MB)

  int total4 = (int)(nd / 4);
  int ptotal = 65536 + total4 + 32 + ZWORDS;
  int pblocks = (ptotal + 255) / 256;
  prep_kernel<<<pblocks + EBLK, 256, 0, stream>>>(x, W1, W2, t, ei, mb, W1f, W2f,
                                                  bnsum, hist, total4, E, nb, pblocks);

  scan_kernel<<<nb, 256, 0, stream>>>(hist, startb, total, nb);
  scatc_kernel<<<EBLK, 256, 0, stream>>>(ei, startb, pairbuf, E, nb);
  agg2_kernel<<<nb, 512, 0, stream>>>(x, mb, pairbuf, total, t, W1f, h0b,
                                      bnsum, bnsumsq, N);

  gemm2_mfma<<<(N + 63) / 64, 256, 0, stream>>>(h0b, W1f, W2f, b2, bnsum, bnsumsq,
                                                bng, bnb, lng, lnb, x, out, N);
}